// Round 8
// baseline (257.796 us; speedup 1.0000x reference)
//
#include <hip/hip_runtime.h>
#include <hip/hip_bf16.h>

// WeightedLoss round 8: LDS-staged gram (m97-style) with k-chunked,
// conflict-free LDS layout; loss recomputes grams (materialization dropped —
// no 278 MB HBM round trip). Direct-global grams (r2-r7) were latency-bound
// at 7% MfmaUtil: 2 waves/SIMD (64 AGPR acc + 108 VGPR) can't hide ~300-cyc
// L2 fragment loads. LDS fragments are ~12 cyc; 4 waves share staged bytes.
// LDS layout [chunk][row][8elem]: global_load_lds stays lane-contiguous and
// ds_read_b128 octets tile all 32 banks (r1's [row][32] had 4-way conflicts).
// ws: [0] Ob bf16 8192x256 | [4 MB] Ln bf16 8192x128 | [6291456] sq f32
//     [6324224] pos_sums | [6356992] neg_sums | [6389760] stats u32[3]

#define B_N 8192
#define NT   64
#define TILE 128
#define NTRI 2080

typedef __attribute__((ext_vector_type(8))) short bf16x8;
typedef __attribute__((ext_vector_type(4))) float f32x4;
typedef __attribute__((ext_vector_type(2))) _Float16 f16x2;

typedef const __attribute__((address_space(1))) void g_void;
typedef __attribute__((address_space(3))) void l_void;

__device__ __forceinline__ unsigned fenc(float f) {
    unsigned u = __float_as_uint(f);
    return (u & 0x80000000u) ? ~u : (u | 0x80000000u);
}
__device__ __forceinline__ float fdec(unsigned k) {
    unsigned u = (k & 0x80000000u) ? (k ^ 0x80000000u) : ~k;
    return __uint_as_float(u);
}

// XCD-swizzled upper-tri decode.
__device__ __forceinline__ void tri_decode_swz(int b, int& bi, int& bj) {
    int t = (b & 7) * (NTRI / 8) + (b >> 3);
    int i = 0, rem = t;
    while (rem >= NT - i) { rem -= NT - i; i++; }
    bi = i; bj = i + rem;
}

// ---------------------------------------------------------------- prep ----
__global__ __launch_bounds__(256) void prep_kernel(
    const float* __restrict__ outputs, const float* __restrict__ labels,
    __hip_bfloat16* __restrict__ Ob, __hip_bfloat16* __restrict__ Ln,
    float* __restrict__ sq, float* __restrict__ pos_sums,
    float* __restrict__ neg_sums, unsigned* __restrict__ stats) {
    int w = threadIdx.x >> 6, lane = threadIdx.x & 63;
    int r = blockIdx.x * 4 + w;
    f32x4 v = ((const f32x4*)outputs)[r * 64 + lane];
    float s = v[0]*v[0] + v[1]*v[1] + v[2]*v[2] + v[3]*v[3];
    #pragma unroll
    for (int m = 1; m < 64; m <<= 1) s += __shfl_xor(s, m);
    if (lane == 0) { sq[r] = s; pos_sums[r] = 0.f; neg_sums[r] = 0.f; }
    __hip_bfloat16 o4[4];
    #pragma unroll
    for (int i = 0; i < 4; i++) o4[i] = __float2bfloat16(v[i]);
    *(uint2*)&Ob[(size_t)r * 256 + lane * 4] = *(uint2*)o4;

    float2 lv = ((const float2*)labels)[r * 64 + lane];
    float ls = lv.x * lv.x + lv.y * lv.y;
    #pragma unroll
    for (int m = 1; m < 64; m <<= 1) ls += __shfl_xor(ls, m);
    float nrm = sqrtf(ls) + 1e-12f;
    __hip_bfloat16 l2[2] = { __float2bfloat16(lv.x / nrm),
                             __float2bfloat16(lv.y / nrm) };
    *(unsigned*)&Ln[(size_t)r * 128 + lane * 2] = *(unsigned*)l2;

    if (blockIdx.x == 0 && threadIdx.x == 0) {
        stats[0] = 0xFFFFFFFFu; stats[1] = 0u; stats[2] = 0u;
    }
}

// --------------------------------------------- LDS-staged 128x128 gram ----
// Block = 4 waves (2x2 of 64x64). Per K=32 slice: stage A+B tiles via
// global_load_lds width-16 into [chunk][row][8] (chunk = k/8), then each
// wave reads conflict-free b128 fragments and runs 16 MFMAs.
template<int KDIM>
__device__ __forceinline__ void gram_lds(
    const __hip_bfloat16* __restrict__ A, const __hip_bfloat16* __restrict__ Bm,
    int rB, int cB, short (*As)[128][8], short (*Bs)[128][8],
    int tid, int l15, int quad, int wm, int wn, f32x4 (&acc)[4][4]) {
    #pragma unroll
    for (int mi = 0; mi < 4; mi++)
        #pragma unroll
        for (int ni = 0; ni < 4; ni++) {
            f32x4 z = {0.f, 0.f, 0.f, 0.f};
            acc[mi][ni] = z;
        }
    int c0 = tid >> 7, r0 = tid & 127;          // flat slot 0..255
    int c1 = c0 + 2, r1 = r0;                   // flat slot 256..511
    #pragma unroll
    for (int k0 = 0; k0 < KDIM; k0 += 32) {
        __syncthreads();   // previous slice's fragment reads done
        const __hip_bfloat16* ga0 = A  + (size_t)(rB + r0) * KDIM + k0 + c0 * 8;
        const __hip_bfloat16* ga1 = A  + (size_t)(rB + r1) * KDIM + k0 + c1 * 8;
        const __hip_bfloat16* gb0 = Bm + (size_t)(cB + r0) * KDIM + k0 + c0 * 8;
        const __hip_bfloat16* gb1 = Bm + (size_t)(cB + r1) * KDIM + k0 + c1 * 8;
        __builtin_amdgcn_global_load_lds((g_void*)ga0, (l_void*)&As[c0][r0][0], 16, 0, 0);
        __builtin_amdgcn_global_load_lds((g_void*)ga1, (l_void*)&As[c1][r1][0], 16, 0, 0);
        __builtin_amdgcn_global_load_lds((g_void*)gb0, (l_void*)&Bs[c0][r0][0], 16, 0, 0);
        __builtin_amdgcn_global_load_lds((g_void*)gb1, (l_void*)&Bs[c1][r1][0], 16, 0, 0);
        __syncthreads();   // staging drained (compiler emits vmcnt(0))
        bf16x8 a[4], b[4];
        #pragma unroll
        for (int mi = 0; mi < 4; mi++)
            a[mi] = *(const bf16x8*)&As[quad][wm + mi * 16 + l15][0];
        #pragma unroll
        for (int ni = 0; ni < 4; ni++)
            b[ni] = *(const bf16x8*)&Bs[quad][wn + ni * 16 + l15][0];
        #pragma unroll
        for (int mi = 0; mi < 4; mi++)
            #pragma unroll
            for (int ni = 0; ni < 4; ni++)
                acc[mi][ni] = __builtin_amdgcn_mfma_f32_16x16x32_bf16(
                    a[mi], b[ni], acc[mi][ni], 0, 0, 0);
    }
}

// ---------------------------------------------------------------- stats ----
__global__ __launch_bounds__(256, 3) void stats_kernel(
    const __hip_bfloat16* __restrict__ Ln, const __hip_bfloat16* __restrict__ Ob,
    const float* __restrict__ sq, unsigned* __restrict__ stats) {
    int bi, bj;
    tri_decode_swz(blockIdx.x, bi, bj);
    int tid = threadIdx.x, lane = tid & 63, wid = tid >> 6;
    int wm = (wid >> 1) * 64, wn = (wid & 1) * 64;
    int l15 = lane & 15, quad = lane >> 4;
    int rB = bi * TILE, cB = bj * TILE;

    __shared__ __align__(16) short As[4][128][8];
    __shared__ __align__(16) short Bs[4][128][8];

    float lmin = 1e30f, lmax = -1e30f, dmax = 0.f;
    f32x4 acc[4][4];

    gram_lds<128>(Ln, Ln, rB, cB, As, Bs, tid, l15, quad, wm, wn, acc);
    #pragma unroll
    for (int mi = 0; mi < 4; mi++)
        #pragma unroll
        for (int ni = 0; ni < 4; ni++)
            #pragma unroll
            for (int r = 0; r < 4; r++) {
                float s = acc[mi][ni][r];
                lmin = fminf(lmin, s);
                lmax = fmaxf(lmax, s);
            }

    gram_lds<256>(Ob, Ob, rB, cB, As, Bs, tid, l15, quad, wm, wn, acc);
    float sqj[4];
    #pragma unroll
    for (int ni = 0; ni < 4; ni++) sqj[ni] = sq[cB + wn + ni * 16 + l15];
    #pragma unroll
    for (int mi = 0; mi < 4; mi++) {
        f32x4 sqi = *(const f32x4*)&sq[rB + wm + mi * 16 + quad * 4];
        #pragma unroll
        for (int r = 0; r < 4; r++)
            #pragma unroll
            for (int ni = 0; ni < 4; ni++) {
                float d2 = fmaxf(sqi[r] + sqj[ni] - 2.f * acc[mi][ni][r], 0.f);
                dmax = fmaxf(dmax, d2);
            }
    }

    #pragma unroll
    for (int m = 1; m < 64; m <<= 1) {
        lmin = fminf(lmin, __shfl_xor(lmin, m));
        lmax = fmaxf(lmax, __shfl_xor(lmax, m));
        dmax = fmaxf(dmax, __shfl_xor(dmax, m));
    }
    __shared__ float red[3][4];
    if ((tid & 63) == 0) { red[0][wid] = lmin; red[1][wid] = lmax; red[2][wid] = dmax; }
    __syncthreads();
    if (tid == 0) {
        lmin = fminf(fminf(red[0][0], red[0][1]), fminf(red[0][2], red[0][3]));
        lmax = fmaxf(fmaxf(red[1][0], red[1][1]), fmaxf(red[1][2], red[1][3]));
        dmax = fmaxf(fmaxf(red[2][0], red[2][1]), fmaxf(red[2][2], red[2][3]));
        atomicMin(&stats[0], fenc(lmin));
        atomicMax(&stats[1], fenc(lmax));
        atomicMax(&stats[2], fenc(dmax));
    }
}

// ----------------------------------------------------------------- loss ----
// gram S -> park raw sim as f16 in padded LDS [col][130] (each wave reads
// back its own writes) -> gram G (same staging buffers) -> fused epilogue.
__global__ __launch_bounds__(256, 3) void loss_kernel(
    const __hip_bfloat16* __restrict__ Ln, const __hip_bfloat16* __restrict__ Ob,
    const float* __restrict__ sq, const unsigned* __restrict__ stats,
    float* __restrict__ pos_sums, float* __restrict__ neg_sums) {
    int bi, bj;
    tri_decode_swz(blockIdx.x, bi, bj);
    int tid = threadIdx.x, lane = tid & 63, wid = tid >> 6;
    int wm = (wid >> 1) * 64, wn = (wid & 1) * 64;
    int l15 = lane & 15, quad = lane >> 4;
    int rB = bi * TILE, cB = bj * TILE;

    __shared__ __align__(16) short As[4][128][8];
    __shared__ __align__(16) short Bs[4][128][8];
    __shared__ _Float16 simL[128][130];
    __shared__ float rP[TILE][2], rN[TILE][2];
    __shared__ float cP[TILE][2], cN[TILE][2];

    f32x4 acc[4][4];

    // --- sim gram; park raw sim in LDS ---
    gram_lds<128>(Ln, Ln, rB, cB, As, Bs, tid, l15, quad, wm, wn, acc);
    #pragma unroll
    for (int mi = 0; mi < 4; mi++)
        #pragma unroll
        for (int ni = 0; ni < 4; ni++) {
            int col = wn + ni * 16 + l15;
            int row0 = wm + mi * 16 + quad * 4;
            #pragma unroll
            for (int p = 0; p < 2; p++) {
                f16x2 v;
                v[0] = (_Float16)acc[mi][ni][2 * p];
                v[1] = (_Float16)acc[mi][ni][2 * p + 1];
                *(f16x2*)&simL[col][row0 + 2 * p] = v;
            }
        }

    // --- outputs gram (reuses As/Bs; its first barrier syncs) ---
    gram_lds<256>(Ob, Ob, rB, cB, As, Bs, tid, l15, quad, wm, wn, acc);

    float smin = fdec(stats[0]);
    float smax = fdec(stats[1]);
    float d2max = fdec(stats[2]);
    float invr = 1.f / (smax - smin);
    float invem = rsqrtf(d2max);

    float sqj[4];
    #pragma unroll
    for (int ni = 0; ni < 4; ni++) sqj[ni] = sq[cB + wn + ni * 16 + l15];
    float cpsum[4] = {0.f, 0.f, 0.f, 0.f};
    float cnsum[4] = {0.f, 0.f, 0.f, 0.f};

    #pragma unroll
    for (int mi = 0; mi < 4; mi++) {
        f32x4 sqi = *(const f32x4*)&sq[rB + wm + mi * 16 + quad * 4];
        float ps[4] = {0.f, 0.f, 0.f, 0.f};
        float ns[4] = {0.f, 0.f, 0.f, 0.f};
        #pragma unroll
        for (int ni = 0; ni < 4; ni++) {
            int col = wn + ni * 16 + l15;
            int row0 = wm + mi * 16 + quad * 4;
            f16x2 s01 = *(f16x2*)&simL[col][row0];
            f16x2 s23 = *(f16x2*)&simL[col][row0 + 2];
            #pragma unroll
            for (int r = 0; r < 4; r++) {
                float sraw = (r < 2) ? (float)s01[r] : (float)s23[r - 2];
                float sn = (sraw - smin) * invr;
                float g = acc[mi][ni][r];
                float d2 = fmaxf(sqi[r] + sqj[ni] - 2.f * g, 0.f);
                float eud = (d2 > 0.f) ? sqrtf(d2) * invem : 0.f;
                float dist = eud + sn;
                bool pos = sn > 0.5f;   // TAU
                float pv = pos ? __expf(dist) : 0.f;
                float nv = pos ? 0.f : __expf(1.0f - dist);  // MAG = 1
                ps[r] += pv;  ns[r] += nv;
                cpsum[ni] += pv;  cnsum[ni] += nv;
            }
        }
        #pragma unroll
        for (int r = 0; r < 4; r++) {
            #pragma unroll
            for (int m = 1; m < 16; m <<= 1) {
                ps[r] += __shfl_xor(ps[r], m);
                ns[r] += __shfl_xor(ns[r], m);
            }
            if (l15 == 0) {
                int rr = wm + mi * 16 + quad * 4 + r;
                rP[rr][wid & 1] = ps[r];
                rN[rr][wid & 1] = ns[r];
            }
        }
    }
    #pragma unroll
    for (int ni = 0; ni < 4; ni++) {
        #pragma unroll
        for (int m = 16; m < 64; m <<= 1) {
            cpsum[ni] += __shfl_xor(cpsum[ni], m);
            cnsum[ni] += __shfl_xor(cnsum[ni], m);
        }
        if (quad == 0) {
            int cc = wn + ni * 16 + l15;
            cP[cc][wid >> 1] = cpsum[ni];
            cN[cc][wid >> 1] = cnsum[ni];
        }
    }
    __syncthreads();
    if (tid < TILE) {
        atomicAdd(&pos_sums[bi * TILE + tid], rP[tid][0] + rP[tid][1]);
        atomicAdd(&neg_sums[bi * TILE + tid], rN[tid][0] + rN[tid][1]);
        if (bi != bj) {
            atomicAdd(&pos_sums[bj * TILE + tid], cP[tid][0] + cP[tid][1]);
            atomicAdd(&neg_sums[bj * TILE + tid], cN[tid][0] + cN[tid][1]);
        }
    }
}

// ------------------------------------------------------------- finalize ----
__global__ __launch_bounds__(256) void finalize_kernel(
    const float* __restrict__ pos_sums, const float* __restrict__ neg_sums,
    float* __restrict__ out) {
    int t = threadIdx.x;
    float acc = 0.f;
    for (int i = t; i < B_N; i += 256) {
        float p = pos_sums[i], n = neg_sums[i];
        float pl = fmaxf(logf(p), 0.f);
        float nl = (n > 0.f) ? fmaxf(logf(n), 0.f) : 0.f;
        acc += pl + nl;
    }
    #pragma unroll
    for (int m = 1; m < 64; m <<= 1) acc += __shfl_xor(acc, m);
    __shared__ float w4[4];
    if ((t & 63) == 0) w4[t >> 6] = acc;
    __syncthreads();
    if (t == 0) out[0] = (w4[0] + w4[1] + w4[2] + w4[3]) / (float)B_N;
}

// ------------------------------------------------------------------ entry ----
extern "C" void kernel_launch(void* const* d_in, const int* in_sizes, int n_in,
                              void* d_out, int out_size, void* d_ws, size_t ws_size,
                              hipStream_t stream) {
    const float* outputs = (const float*)d_in[0];
    const float* labels  = (const float*)d_in[1];
    float* out = (float*)d_out;
    char* ws = (char*)d_ws;
    __hip_bfloat16* Ob = (__hip_bfloat16*)(ws);
    __hip_bfloat16* Ln = (__hip_bfloat16*)(ws + 4194304);
    float* sq          = (float*)(ws + 6291456);
    float* pos_sums    = (float*)(ws + 6324224);
    float* neg_sums    = (float*)(ws + 6356992);
    unsigned* stats    = (unsigned*)(ws + 6389760);

    prep_kernel<<<B_N / 4, 256, 0, stream>>>(outputs, labels, Ob, Ln, sq,
                                             pos_sums, neg_sums, stats);
    stats_kernel<<<NTRI, 256, 0, stream>>>(Ln, Ob, sq, stats);
    loss_kernel<<<NTRI, 256, 0, stream>>>(Ln, Ob, sq, stats,
                                          pos_sums, neg_sums);
    finalize_kernel<<<1, 256, 0, stream>>>(pos_sums, neg_sums, out);
}